// Round 5
// baseline (799.075 us; speedup 1.0000x reference)
//
#include <hip/hip_runtime.h>

#define E_DIM   2048
#define NHEADS  16
#define NBATCH  4
#define SLEN    2048
#define TLEN    2048
#define DHEAD   128
#define MROWS   (NBATCH * SLEN)   // 8192

typedef __bf16  bf16x8  __attribute__((ext_vector_type(8)));
typedef __bf16  bf16x4  __attribute__((ext_vector_type(4)));
typedef float   floatx4 __attribute__((ext_vector_type(4)));
typedef unsigned short ushort8_v __attribute__((ext_vector_type(8)));

// fp32 -> bf16 RTNE via compiler cast (emits v_cvt_pk_bf16_f32 pairs; m240:
// scalar cast beats hand-written bit-math/inline-asm cvt_pk)
__device__ __forceinline__ unsigned short f2bf(float f) {
    return __builtin_bit_cast(unsigned short, (__bf16)f);
}

// async global->LDS, 16 B per lane: LDS dest = wave-uniform base + lane*16
__device__ __forceinline__ void gload16(const unsigned short* g, unsigned short* l) {
    __builtin_amdgcn_global_load_lds(
        (const __attribute__((address_space(1))) unsigned int*)(const void*)g,
        (__attribute__((address_space(3))) unsigned int*)(void*)l, 16, 0, 0);
}

// ---------------------------------------------------------------------------
// fp32 -> bf16 conversion kernels
// ---------------------------------------------------------------------------
__global__ __launch_bounds__(256)
void conv_qkv(const float* __restrict__ q, const float* __restrict__ k,
              const float* __restrict__ v, unsigned short* __restrict__ dst)
{
    const float* src = (blockIdx.y == 0) ? q : ((blockIdx.y == 1) ? k : v);
    const size_t base = (size_t)blockIdx.y * ((size_t)MROWS * E_DIM);
    const size_t i = ((size_t)blockIdx.x * 256 + threadIdx.x) * 8;
    const float4 a = *(const float4*)(src + i);
    const float4 b = *(const float4*)(src + i + 4);
    ushort8_v o;
    o[0]=f2bf(a.x); o[1]=f2bf(a.y); o[2]=f2bf(a.z); o[3]=f2bf(a.w);
    o[4]=f2bf(b.x); o[5]=f2bf(b.y); o[6]=f2bf(b.z); o[7]=f2bf(b.w);
    *(ushort8_v*)(dst + base + i) = o;
}

__global__ __launch_bounds__(256)
void conv_w(const float* __restrict__ w0, const float* __restrict__ w1,
            const float* __restrict__ w2, const float* __restrict__ w3,
            unsigned short* __restrict__ dst)
{
    const float* src = (blockIdx.y == 0) ? w0 : ((blockIdx.y == 1) ? w1 :
                       ((blockIdx.y == 2) ? w2 : w3));
    const size_t base = (size_t)blockIdx.y * ((size_t)E_DIM * E_DIM);
    const size_t i = ((size_t)blockIdx.x * 256 + threadIdx.x) * 8;
    const float4 a = *(const float4*)(src + i);
    const float4 b = *(const float4*)(src + i + 4);
    ushort8_v o;
    o[0]=f2bf(a.x); o[1]=f2bf(a.y); o[2]=f2bf(a.z); o[3]=f2bf(a.w);
    o[4]=f2bf(b.x); o[5]=f2bf(b.y); o[6]=f2bf(b.z); o[7]=f2bf(b.w);
    *(ushort8_v*)(dst + base + i) = o;
}

// ---------------------------------------------------------------------------
// GEMM: C[M,Nd] = (A[M,K] * B[Nd,K]^T + bias) * scale. A,B bf16. m97 pattern:
// global_load_lds width=16, unpadded [128][32] LDS, XOR chunk swizzle
// (phys = log ^ ((row>>1)&3)) -> 2-way banks (free) on ds_read_b128.
// EPI: 0 = fp32 std layout, 1 = bf16 std layout, 2 = bf16 direct-V^T layout.
// ---------------------------------------------------------------------------
template<int EPI>
__global__ __launch_bounds__(256, 2)
void gemm_bt(const unsigned short* __restrict__ A, const unsigned short* __restrict__ B,
             const float* __restrict__ bias, void* __restrict__ Cv,
             int M, int Nd, int K, float scale)
{
    __shared__ unsigned short As[128 * 32];
    __shared__ unsigned short Bs[128 * 32];

    const int tid  = threadIdx.x;
    const int bm   = blockIdx.x * 128;
    const int bn   = blockIdx.y * 128;
    const int wave = tid >> 6, lane = tid & 63;
    const int wm   = (wave >> 1) * 64, wn = (wave & 1) * 64;
    const int lrow = lane & 15, quad = lane >> 4;

    // staging lane mapping: row = lane/4, physical chunk = lane%4
    const int srow = lane >> 2, schk = lane & 3;
    const int slog = schk ^ ((srow >> 1) & 3);           // logical chunk in global
    const unsigned short* ag = A + (size_t)(bm + wave * 32 + srow) * K + slog * 8;
    const unsigned short* bg = B + (size_t)(bn + wave * 32 + srow) * K + slog * 8;
    unsigned short* lA0 = &As[(wave * 32) * 32];
    unsigned short* lA1 = &As[(wave * 32 + 16) * 32];
    unsigned short* lB0 = &Bs[(wave * 32) * 32];
    unsigned short* lB1 = &Bs[(wave * 32 + 16) * 32];

    const int aswz = (quad ^ ((lrow >> 1) & 3)) * 8;     // read-side physical chunk

    floatx4 acc[4][4] = {};

    for (int k0 = 0; k0 < K; k0 += 32) {
        gload16(ag + k0,                  lA0);
        gload16(ag + (size_t)16 * K + k0, lA1);
        gload16(bg + k0,                  lB0);
        gload16(bg + (size_t)16 * K + k0, lB1);
        __syncthreads();   // drains vmcnt -> staged data visible

        bf16x8 af[4], bfr[4];
        #pragma unroll
        for (int mi = 0; mi < 4; ++mi)
            af[mi] = *(const bf16x8*)&As[(wm + mi * 16 + lrow) * 32 + aswz];
        #pragma unroll
        for (int ni = 0; ni < 4; ++ni)
            bfr[ni] = *(const bf16x8*)&Bs[(wn + ni * 16 + lrow) * 32 + aswz];
        #pragma unroll
        for (int mi = 0; mi < 4; ++mi)
            #pragma unroll
            for (int ni = 0; ni < 4; ++ni)
                acc[mi][ni] = __builtin_amdgcn_mfma_f32_16x16x32_bf16(af[mi], bfr[ni], acc[mi][ni], 0, 0, 0);
        __syncthreads();
    }

    // epilogue: C/D layout col=lane&15, row=quad*4+i
    #pragma unroll
    for (int ni = 0; ni < 4; ++ni) {
        const int col = bn + wn + ni * 16 + lrow;
        const float bv = bias[col];
        #pragma unroll
        for (int mi = 0; mi < 4; ++mi) {
            const int row = bm + wm + mi * 16 + quad * 4;
            if constexpr (EPI == 2) {
                // write V^T directly: (N,T,E)[row=(n,t), col=(h,d)] -> Vt(N,H,D,T)
                const int n = row >> 11, t = row & 2047;
                const int hh = col >> 7, dd = col & 127;
                unsigned short* dst = (unsigned short*)Cv +
                    (((size_t)(n * 16 + hh) * 128 + dd) * 2048 + t);
                ushort4 w;
                w.x = f2bf((acc[mi][ni][0] + bv) * scale);
                w.y = f2bf((acc[mi][ni][1] + bv) * scale);
                w.z = f2bf((acc[mi][ni][2] + bv) * scale);
                w.w = f2bf((acc[mi][ni][3] + bv) * scale);
                *(ushort4*)dst = w;   // 4 consecutive t, 8B aligned
            } else {
                #pragma unroll
                for (int i = 0; i < 4; ++i) {
                    const float v = (acc[mi][ni][i] + bv) * scale;
                    if constexpr (EPI == 1)
                        ((unsigned short*)Cv)[(size_t)(row + i) * Nd + col] = f2bf(v);
                    else
                        ((float*)Cv)[(size_t)(row + i) * Nd + col] = v;
                }
            }
        }
    }
}

// ---------------------------------------------------------------------------
// Mask tile summary: per 128x128 tile of mask[T,S]: 0=all-zero, 1=mixed, 2=all-ones
// ---------------------------------------------------------------------------
__global__ __launch_bounds__(256)
void mask_tiles(const int* __restrict__ mask, unsigned char* __restrict__ flags)
{
    __shared__ int s_and, s_or;
    const int tid = threadIdx.x;
    if (tid == 0) { s_and = 1; s_or = 0; }
    __syncthreads();
    const int tt = blockIdx.x >> 4;
    const int ss = blockIdx.x & 15;
    int la = 1, lo = 0;
    #pragma unroll
    for (int it = 0; it < 16; ++it) {
        const int c = it * 256 + tid;
        const int row = c >> 5, c4 = c & 31;
        const int4 v = *(const int4*)(mask + (size_t)(tt * 128 + row) * SLEN + ss * 128 + c4 * 4);
        const int nz = (v.x != 0) + (v.y != 0) + (v.z != 0) + (v.w != 0);
        la &= (nz == 4); lo |= (nz != 0);
    }
    if (!la) atomicAnd(&s_and, 0);
    if (lo)  atomicOr(&s_or, 1);
    __syncthreads();
    if (tid == 0) flags[blockIdx.x] = (unsigned char)(s_and ? 2 : (s_or ? 1 : 0));
}

// ---------------------------------------------------------------------------
// Flash attention, transposed scores. Q pre-scaled by (1/sqrt(d))*log2(e).
// QK^T computed as S^T = K·Q^T -> C-layout lane holds [t=ti*16+quad*4+i][s=si*16+lrow].
// K/V tiles staged with global_load_lds (linear [128][128] LDS dest) with
// both-sides 16B-unit XOR swizzle: phys_unit = log_unit ^ (row&7). Stage side
// pre-swizzles the GLOBAL source address (rule #21); read side XORs the unit.
// ds_read_b128 then spreads 8 rows over 8 distinct 16B slots -> <=2-way (free).
// Defer-max (T13, THR=8 in log2 units): skip O-rescale + m update while the
// tile max stays within 8 of the running max (P bounded by 2^8, exact in fp32).
// T1 XCD chunk swizzle: 16 s-tiles share each (n,h)'s K/V (1MB); chunked remap
// colocates them on one XCD -> per-iter working set ~512KB << 4MB L2 (vs ~4MB+
// thrash under round-robin). 1024 % 8 == 0 -> bijective.
// P staged per-wave in 32-wide chunks fused with PV (Ps = 10 KB). 74 KB LDS
// -> 2 blocks/CU.
// ---------------------------------------------------------------------------
#define LDP2 40    // P chunk row stride (80 B)

__global__ __launch_bounds__(256, 2)
void flash_attn(const unsigned short* __restrict__ Q,
                const unsigned short* __restrict__ Kb,
                const unsigned short* __restrict__ Vt,
                const int* __restrict__ mask,
                const unsigned char* __restrict__ tflags,
                unsigned short* __restrict__ O)
{
    __shared__ __align__(16) unsigned short Ks[128 * 128];
    __shared__ __align__(16) unsigned short Vs[128 * 128];
    __shared__ __align__(16) unsigned short Ps[4][32 * LDP2];

    const int tid  = threadIdx.x;
    // T1 XCD chunk swizzle on the linear dispatch id (x fastest):
    // xcd = lin%8 gets contiguous chunk of 128 blocks = 8 full (n,h) groups.
    const int lin  = blockIdx.x + 16 * (blockIdx.y + 16 * blockIdx.z);
    const int nlin = (lin & 7) * 128 + (lin >> 3);
    const int s0   = (nlin & 15) * 128;
    const int h    = (nlin >> 4) & 15;
    const int n    = nlin >> 8;
    const int wave = tid >> 6, lane = tid & 63;
    const int lrow = lane & 15, quad = lane >> 4;
    const int qbase = s0 + wave * 32;

    // staging lane mapping: 1 issue = 4 rows x 256 B; lane covers 16 B unit
    const int sr4 = lane >> 4;      // row within issue (0..3)
    const int su  = lane & 15;      // physical 16B unit within row

    const unsigned short* Kbase = Kb + (size_t)n * TLEN * NHEADS * DHEAD + (size_t)h * DHEAD;
    const unsigned short* Vbase = Vt + ((size_t)(n * NHEADS + h) * DHEAD) * TLEN;

    // Q fragments (B-operand layout == A layout: n=lane&15, k=quad*8+j)
    bf16x8 aq[2][4];
    #pragma unroll
    for (int si = 0; si < 2; ++si)
        #pragma unroll
        for (int kk = 0; kk < 4; ++kk)
            aq[si][kk] = *(const bf16x8*)(Q + ((size_t)(n * SLEN + qbase + si * 16 + lrow) * NHEADS + h) * DHEAD
                                            + kk * 32 + quad * 8);

    float m_r[2] = { -INFINITY, -INFINITY };
    float l_r[2] = { 0.f, 0.f };
    floatx4 occ[2][8] = {};

    for (int t0 = 0; t0 < TLEN; t0 += 128) {
        const int flag = tflags[(t0 >> 7) * (SLEN >> 7) + (s0 >> 7)];
        if (flag == 0) continue;   // uniform per block

        // stage K tile [t][d] and V^T tile [d][t] via global_load_lds.
        // LDS dest linear; global source pre-swizzled: unit = su ^ (row&7).
        #pragma unroll
        for (int i = 0; i < 8; ++i) {
            const int rb = wave * 32 + i * 4;        // wave-uniform base row
            const int r  = rb + sr4;                 // this lane's row
            const int uo = ((su ^ (r & 7)) * 8);     // element offset of 16B unit
            gload16(Kbase + (size_t)(t0 + r) * (NHEADS * DHEAD) + uo, &Ks[rb * 128]);
            gload16(Vbase + (size_t)r * TLEN + t0 + uo,              &Vs[rb * 128]);
        }
        __syncthreads();   // drains vmcnt -> staged data visible

        // S^T = K * Q^T : D[m=t][n=s]
        floatx4 sacc[8][2] = {};
        __builtin_amdgcn_s_setprio(1);
        #pragma unroll
        for (int kk = 0; kk < 4; ++kk)
            #pragma unroll
            for (int ti = 0; ti < 8; ++ti) {
                const bf16x8 ak = *(const bf16x8*)&Ks[(ti * 16 + lrow) * 128
                                                      + ((kk * 4 + quad) ^ (lrow & 7)) * 8];
                sacc[ti][0] = __builtin_amdgcn_mfma_f32_16x16x32_bf16(ak, aq[0][kk], sacc[ti][0], 0, 0, 0);
                sacc[ti][1] = __builtin_amdgcn_mfma_f32_16x16x32_bf16(ak, aq[1][kk], sacc[ti][1], 0, 0, 0);
            }
        __builtin_amdgcn_s_setprio(0);

        if (flag == 1) {
            #pragma unroll
            for (int ti = 0; ti < 8; ++ti)
                #pragma unroll
                for (int si = 0; si < 2; ++si)
                    #pragma unroll
                    for (int i = 0; i < 4; ++i) {
                        const int t = t0 + ti * 16 + quad * 4 + i;
                        const int s = s0 + wave * 32 + si * 16 + lrow;
                        if (mask[(size_t)t * SLEN + s] == 0) sacc[ti][si][i] = -INFINITY;
                    }
        }

        // row stats: in-lane over (ti,i), then across quads (xor 16, 32)
        float mt[2];
        #pragma unroll
        for (int si = 0; si < 2; ++si) {
            float v = sacc[0][si][0];
            #pragma unroll
            for (int ti = 0; ti < 8; ++ti)
                #pragma unroll
                for (int i = 0; i < 4; ++i) v = fmaxf(v, sacc[ti][si][i]);
            v = fmaxf(v, __shfl_xor(v, 16));
            v = fmaxf(v, __shfl_xor(v, 32));
            mt[si] = v;
        }

        // defer-max: only rescale when the tile max overshoots by >8 (log2).
        // Wave-uniform (__any) -> no divergence; P then bounded by 2^8.
        float alpha[2] = { 1.f, 1.f };
        if (__any((mt[0] > m_r[0] + 8.f) || (mt[1] > m_r[1] + 8.f))) {
            float ao[2][4];
            #pragma unroll
            for (int si = 0; si < 2; ++si) {
                const float mnew = fmaxf(m_r[si], mt[si]);
                alpha[si] = (mnew == -INFINITY) ? 0.f : exp2f(m_r[si] - mnew);
                m_r[si] = mnew;
                #pragma unroll
                for (int i = 0; i < 4; ++i)
                    ao[si][i] = __shfl(alpha[si], quad * 4 + i);   // s = si*16+quad*4+i
            }
            #pragma unroll
            for (int si = 0; si < 2; ++si)
                #pragma unroll
                for (int nd = 0; nd < 8; ++nd)
                    #pragma unroll
                    for (int i = 0; i < 4; ++i)
                        occ[si][nd][i] *= ao[si][i];
        }
        // hoisted -INF gate: m_r==-INF implies all sacc==-INF -> exp2(-INF)=0
        const float msub[2] = { (m_r[0] == -INFINITY) ? 0.f : m_r[0],
                                (m_r[1] == -INFINITY) ? 0.f : m_r[1] };

        // fused exp + P-chunk staging + PV (per-wave Ps: same-wave DS ordering, no barrier)
        float psum[2] = { 0.f, 0.f };
        #pragma unroll
        for (int kk = 0; kk < 4; ++kk) {
            #pragma unroll
            for (int si = 0; si < 2; ++si)
                #pragma unroll
                for (int half = 0; half < 2; ++half) {
                    const int ti = kk * 2 + half;
                    float p[4];
                    #pragma unroll
                    for (int i = 0; i < 4; ++i)
                        p[i] = exp2f(sacc[ti][si][i] - msub[si]);
                    psum[si] += (p[0] + p[1]) + (p[2] + p[3]);
                    bf16x4 pb;
                    pb[0] = (__bf16)p[0]; pb[1] = (__bf16)p[1];
                    pb[2] = (__bf16)p[2]; pb[3] = (__bf16)p[3];
                    *(bf16x4*)&Ps[wave][(si * 16 + lrow) * LDP2 + half * 16 + quad * 4] = pb;
                }
            bf16x8 ap[2];
            #pragma unroll
            for (int si = 0; si < 2; ++si)
                ap[si] = *(const bf16x8*)&Ps[wave][(si * 16 + lrow) * LDP2 + quad * 8];
            __builtin_amdgcn_s_setprio(1);
            #pragma unroll
            for (int nd = 0; nd < 8; ++nd) {
                const bf16x8 bv = *(const bf16x8*)&Vs[(nd * 16 + lrow) * 128
                                                      + ((kk * 4 + quad) ^ (lrow & 7)) * 8];
                occ[0][nd] = __builtin_amdgcn_mfma_f32_16x16x32_bf16(ap[0], bv, occ[0][nd], 0, 0, 0);
                occ[1][nd] = __builtin_amdgcn_mfma_f32_16x16x32_bf16(ap[1], bv, occ[1][nd], 0, 0, 0);
            }
            __builtin_amdgcn_s_setprio(0);
        }

        #pragma unroll
        for (int si = 0; si < 2; ++si) {
            psum[si] += __shfl_xor(psum[si], 16);
            psum[si] += __shfl_xor(psum[si], 32);
            l_r[si] = l_r[si] * alpha[si] + psum[si];
        }
        __syncthreads();
    }

    // normalize (broadcast 1/l to O layout) and store O (N,S,H,D) bf16
    float rl[2];
    #pragma unroll
    for (int si = 0; si < 2; ++si)
        rl[si] = (l_r[si] > 0.f) ? 1.0f / l_r[si] : 0.f;
    float rlo[2][4];
    #pragma unroll
    for (int si = 0; si < 2; ++si)
        #pragma unroll
        for (int i = 0; i < 4; ++i)
            rlo[si][i] = __shfl(rl[si], quad * 4 + i);

    #pragma unroll
    for (int si = 0; si < 2; ++si)
        #pragma unroll
        for (int nd = 0; nd < 8; ++nd)
            #pragma unroll
            for (int i = 0; i < 4; ++i) {
                const int srow = s0 + wave * 32 + si * 16 + quad * 4 + i;
                O[((size_t)(n * SLEN + srow) * NHEADS + h) * DHEAD + nd * 16 + lrow] =
                    f2bf(occ[si][nd][i] * rlo[si][i]);
            }
}

// ---------------------------------------------------------------------------
extern "C" void kernel_launch(void* const* d_in, const int* in_sizes, int n_in,
                              void* d_out, int out_size, void* d_ws, size_t ws_size,
                              hipStream_t stream)
{
    const float* query = (const float*)d_in[0];
    const float* key   = (const float*)d_in[1];
    const float* value = (const float*)d_in[2];
    const int*   mask  = (const int*)d_in[3];
    const float* Wq = (const float*)d_in[4];  const float* bq = (const float*)d_in[5];
    const float* Wk = (const float*)d_in[6];  const float* bk = (const float*)d_in[7];
    const float* Wv = (const float*)d_in[8];  const float* bv = (const float*)d_in[9];
    const float* Wp = (const float*)d_in[10]; const float* bp = (const float*)d_in[11];
    float* out = (float*)d_out;

    // ws layout (128 MB + 256 B): [Wb 32MB][A 32MB][B 32MB][C 32MB][flags]
    char* ws = (char*)d_ws;
    const size_t SLOT = 32ull * 1024 * 1024;
    unsigned short* Wb  = (unsigned short*)ws;              // 4 bf16 weights
    unsigned short* Abf = (unsigned short*)(ws + SLOT);     // q_bf -> later V^T
    unsigned short* Bbf = (unsigned short*)(ws + 2 * SLOT); // k_bf
    unsigned short* Cbf = (unsigned short*)(ws + 3 * SLOT); // v_bf -> later attn out
    unsigned char*  flags = (unsigned char*)(ws + 4 * SLOT);
    // Q/K projections parked in d_out (64 MB, dead before final GEMM writes it)
    unsigned short* Qb  = (unsigned short*)d_out;
    unsigned short* Kbb = (unsigned short*)((char*)d_out + SLOT);

    const size_t WSLOT = (size_t)E_DIM * E_DIM;
    const dim3 gg(MROWS / 128, E_DIM / 128);
    const float sc = 0.08838834764831845f * 1.4426950408889634f; // 1/sqrt(128)*log2(e)

    mask_tiles<<<256, 256, 0, stream>>>(mask, flags);
    conv_qkv<<<dim3(8192, 3), 256, 0, stream>>>(query, key, value, Abf);
    conv_w<<<dim3(2048, 4), 256, 0, stream>>>(Wq, Wk, Wv, Wp, Wb);

    gemm_bt<1><<<gg, 256, 0, stream>>>(Abf, Wb,             bq, Qb,  MROWS, E_DIM, E_DIM, sc);
    gemm_bt<1><<<gg, 256, 0, stream>>>(Bbf, Wb + WSLOT,     bk, Kbb, MROWS, E_DIM, E_DIM, 1.f);
    gemm_bt<2><<<gg, 256, 0, stream>>>(Cbf, Wb + 2 * WSLOT, bv, Abf, MROWS, E_DIM, E_DIM, 1.f);
    flash_attn<<<dim3(SLEN / 128, NHEADS, NBATCH), 256, 0, stream>>>(Qb, Kbb, Abf, mask, flags, Cbf);
    gemm_bt<0><<<gg, 256, 0, stream>>>(Cbf, Wb + 3 * WSLOT, bp, out, MROWS, E_DIM, E_DIM, 1.f);
}

// Round 10
// 784.141 us; speedup vs baseline: 1.0190x; 1.0190x over previous
//
#include <hip/hip_runtime.h>

#define E_DIM   2048
#define NHEADS  16
#define NBATCH  4
#define SLEN    2048
#define TLEN    2048
#define DHEAD   128
#define MROWS   (NBATCH * SLEN)   // 8192

typedef __bf16  bf16x8  __attribute__((ext_vector_type(8)));
typedef __bf16  bf16x4  __attribute__((ext_vector_type(4)));
typedef float   floatx4 __attribute__((ext_vector_type(4)));
typedef unsigned short ushort8_v __attribute__((ext_vector_type(8)));

// fp32 -> bf16 RTNE via compiler cast
__device__ __forceinline__ unsigned short f2bf(float f) {
    return __builtin_bit_cast(unsigned short, (__bf16)f);
}

// async global->LDS, 16 B per lane: LDS dest = wave-uniform base + lane*16
__device__ __forceinline__ void gload16(const unsigned short* g, unsigned short* l) {
    __builtin_amdgcn_global_load_lds(
        (const __attribute__((address_space(1))) unsigned int*)(const void*)g,
        (__attribute__((address_space(3))) unsigned int*)(void*)l, 16, 0, 0);
}

// raw barrier with compile-time memory fences (no vmcnt(0) drain, unlike
// __syncthreads; fences stop LDS-op motion across the barrier at zero cost)
__device__ __forceinline__ void bar() {
    asm volatile("" ::: "memory");
    __builtin_amdgcn_s_barrier();
    asm volatile("" ::: "memory");
}

// ---------------------------------------------------------------------------
// fp32 -> bf16 conversion kernels
// ---------------------------------------------------------------------------
__global__ __launch_bounds__(256)
void conv_qkv(const float* __restrict__ q, const float* __restrict__ k,
              const float* __restrict__ v, unsigned short* __restrict__ dst)
{
    const float* src = (blockIdx.y == 0) ? q : ((blockIdx.y == 1) ? k : v);
    const size_t base = (size_t)blockIdx.y * ((size_t)MROWS * E_DIM);
    const size_t i = ((size_t)blockIdx.x * 256 + threadIdx.x) * 8;
    const float4 a = *(const float4*)(src + i);
    const float4 b = *(const float4*)(src + i + 4);
    ushort8_v o;
    o[0]=f2bf(a.x); o[1]=f2bf(a.y); o[2]=f2bf(a.z); o[3]=f2bf(a.w);
    o[4]=f2bf(b.x); o[5]=f2bf(b.y); o[6]=f2bf(b.z); o[7]=f2bf(b.w);
    *(ushort8_v*)(dst + base + i) = o;
}

__global__ __launch_bounds__(256)
void conv_w(const float* __restrict__ w0, const float* __restrict__ w1,
            const float* __restrict__ w2, const float* __restrict__ w3,
            unsigned short* __restrict__ dst)
{
    const float* src = (blockIdx.y == 0) ? w0 : ((blockIdx.y == 1) ? w1 :
                       ((blockIdx.y == 2) ? w2 : w3));
    const size_t base = (size_t)blockIdx.y * ((size_t)E_DIM * E_DIM);
    const size_t i = ((size_t)blockIdx.x * 256 + threadIdx.x) * 8;
    const float4 a = *(const float4*)(src + i);
    const float4 b = *(const float4*)(src + i + 4);
    ushort8_v o;
    o[0]=f2bf(a.x); o[1]=f2bf(a.y); o[2]=f2bf(a.z); o[3]=f2bf(a.w);
    o[4]=f2bf(b.x); o[5]=f2bf(b.y); o[6]=f2bf(b.z); o[7]=f2bf(b.w);
    *(ushort8_v*)(dst + base + i) = o;
}

// ---------------------------------------------------------------------------
// 256x256 8-phase GEMM: C[M,Nd] = (A[M,K]*B[Nd,K]^T + bias)*scale, bf16 in.
// T3+T4 structure: BK=64, 512 thr (8 waves 2Mx4N), 128KB dbuf LDS, counted
// vmcnt (never 0 in loop), 4 phases/K-tile x 16 MFMA, T5 setprio.
// LDS swizzle: phys_unit = log_unit ^ (row&7) both-sides involution ->
// ds_read_b128 per quarter-wave: 8 distinct units x 2 lanes = 2-way (free);
// gload_lds dest linear, global source pre-swizzled (rule #21).
// Next-tile issue order: P1:B0,B1  P2:B2,B3  P3:A0,A2  P4:A1,A3 (64-row issues).
// FIFO accounting: end-P4 vmcnt(2) retires {B0..B3,A0,A2} = exactly what the
// next tile's P1/P3 read; end-P1 vmcnt(2) retires {A1,A3} for P2/P4. Each wait
// sits BEFORE the phase barrier so all waves' slices are confirmed before any
// wave reads them.
// EPI: 0 = fp32 std layout, 1 = bf16 std layout, 2 = bf16 direct-V^T layout.
// ---------------------------------------------------------------------------
template<int EPI>
__global__ __launch_bounds__(512, 2)
void gemm256(const unsigned short* __restrict__ A, const unsigned short* __restrict__ B,
             const float* __restrict__ bias, void* __restrict__ Cv,
             int M, int Nd, int K, float scale)
{
    __shared__ unsigned short As[2 * 256 * 64];   // 64 KB
    __shared__ unsigned short Bs[2 * 256 * 64];   // 64 KB

    const int tid  = threadIdx.x;
    const int bm   = blockIdx.x * 256;
    const int bn   = blockIdx.y * 256;
    const int wave = tid >> 6, lane = tid & 63;
    const int wm   = (wave >> 2) * 128;           // 2 wave-rows
    const int wn   = (wave & 3) * 64;             // 4 wave-cols
    const int lrow = lane & 15, quad = lane >> 4;
    const int u0   = (quad ^ (lrow & 7)) * 8;         // kk=0 phys unit offset
    const int u1   = ((4 + quad) ^ (lrow & 7)) * 8;   // kk=1

    // staging: thread covers LDS row (issue*64 + tid>>3), phys unit tid&7;
    // global source col = (phys ^ (row&7)) * 8  (both-sides involution)
    const int srow = tid >> 3;
    const int scol = ((tid & 7) ^ (srow & 7)) * 8;
    const unsigned short* ag = A + (size_t)(bm + srow) * K + scol;
    const unsigned short* bg = B + (size_t)(bn + srow) * K + scol;
    const size_t R64 = (size_t)64 * K, R128 = (size_t)128 * K, R192 = (size_t)192 * K;
    const int ldsw = wave * 8 * 64;               // wave slice within an issue

    floatx4 acc[8][4] = {};
    const int nt = K / 64;

    // prologue: tile 0 -> buf0, order B0,B1,B2,B3,A0,A2,A1,A3
    gload16(bg,        &Bs[0 * 4096 + ldsw]);
    gload16(bg + R64,  &Bs[1 * 4096 + ldsw]);
    gload16(bg + R128, &Bs[2 * 4096 + ldsw]);
    gload16(bg + R192, &Bs[3 * 4096 + ldsw]);
    gload16(ag,        &As[0 * 4096 + ldsw]);
    gload16(ag + R128, &As[2 * 4096 + ldsw]);
    gload16(ag + R64,  &As[1 * 4096 + ldsw]);
    gload16(ag + R192, &As[3 * 4096 + ldsw]);
    asm volatile("s_waitcnt vmcnt(2)" ::: "memory");   // first 6 landed; A1,A3 in flight
    bar();

    for (int t = 0; t < nt; ++t) {
        const unsigned short* as = &As[(t & 1) * 16384];
        const unsigned short* bs = &Bs[(t & 1) * 16384];
        unsigned short* aD = &As[((t + 1) & 1) * 16384];
        unsigned short* bD = &Bs[((t + 1) & 1) * 16384];
        const int k1 = (t + 1) * 64;
        const bool pf = (t + 1 < nt);

        bf16x8 af[4], bf[4];

        // ---------- P1: kk=0, mi 0..3 ----------
        #pragma unroll
        for (int i = 0; i < 4; ++i)
            af[i] = *(const bf16x8*)&as[(wm + i * 16 + lrow) * 64 + u0];
        #pragma unroll
        for (int i = 0; i < 4; ++i)
            bf[i] = *(const bf16x8*)&bs[(wn + i * 16 + lrow) * 64 + u0];
        if (pf) { gload16(bg + k1,       bD + 0 * 4096 + ldsw);
                  gload16(bg + R64 + k1, bD + 1 * 4096 + ldsw); }
        bar();
        __builtin_amdgcn_s_setprio(1);
        #pragma unroll
        for (int i = 0; i < 4; ++i)
            #pragma unroll
            for (int ni = 0; ni < 4; ++ni)
                acc[i][ni] = __builtin_amdgcn_mfma_f32_16x16x32_bf16(af[i], bf[ni], acc[i][ni], 0, 0, 0);
        __builtin_amdgcn_s_setprio(0);
        if (pf) asm volatile("s_waitcnt vmcnt(2)" ::: "memory");  // A1,A3 of cur landed
        else    asm volatile("s_waitcnt vmcnt(0)" ::: "memory");  // final drain
        bar();

        // ---------- P2: kk=0, mi 4..7 ----------
        #pragma unroll
        for (int i = 0; i < 4; ++i)
            af[i] = *(const bf16x8*)&as[(wm + 64 + i * 16 + lrow) * 64 + u0];
        if (pf) { gload16(bg + R128 + k1, bD + 2 * 4096 + ldsw);
                  gload16(bg + R192 + k1, bD + 3 * 4096 + ldsw); }
        bar();
        __builtin_amdgcn_s_setprio(1);
        #pragma unroll
        for (int i = 0; i < 4; ++i)
            #pragma unroll
            for (int ni = 0; ni < 4; ++ni)
                acc[4 + i][ni] = __builtin_amdgcn_mfma_f32_16x16x32_bf16(af[i], bf[ni], acc[4 + i][ni], 0, 0, 0);
        __builtin_amdgcn_s_setprio(0);
        bar();

        // ---------- P3: kk=1, mi 0..3 ----------
        #pragma unroll
        for (int i = 0; i < 4; ++i)
            af[i] = *(const bf16x8*)&as[(wm + i * 16 + lrow) * 64 + u1];
        #pragma unroll
        for (int i = 0; i < 4; ++i)
            bf[i] = *(const bf16x8*)&bs[(wn + i * 16 + lrow) * 64 + u1];
        if (pf) { gload16(ag + k1,        aD + 0 * 4096 + ldsw);
                  gload16(ag + R128 + k1, aD + 2 * 4096 + ldsw); }
        bar();
        __builtin_amdgcn_s_setprio(1);
        #pragma unroll
        for (int i = 0; i < 4; ++i)
            #pragma unroll
            for (int ni = 0; ni < 4; ++ni)
                acc[i][ni] = __builtin_amdgcn_mfma_f32_16x16x32_bf16(af[i], bf[ni], acc[i][ni], 0, 0, 0);
        __builtin_amdgcn_s_setprio(0);
        bar();

        // ---------- P4: kk=1, mi 4..7 ----------
        #pragma unroll
        for (int i = 0; i < 4; ++i)
            af[i] = *(const bf16x8*)&as[(wm + 64 + i * 16 + lrow) * 64 + u1];
        if (pf) { gload16(ag + R64 + k1,  aD + 1 * 4096 + ldsw);
                  gload16(ag + R192 + k1, aD + 3 * 4096 + ldsw); }
        bar();
        __builtin_amdgcn_s_setprio(1);
        #pragma unroll
        for (int i = 0; i < 4; ++i)
            #pragma unroll
            for (int ni = 0; ni < 4; ++ni)
                acc[4 + i][ni] = __builtin_amdgcn_mfma_f32_16x16x32_bf16(af[i], bf[ni], acc[4 + i][ni], 0, 0, 0);
        __builtin_amdgcn_s_setprio(0);
        if (pf) asm volatile("s_waitcnt vmcnt(2)" ::: "memory");  // next tile's first-6 landed
        bar();
    }

    // epilogue: C/D layout col=lane&15, row=quad*4+i
    #pragma unroll
    for (int ni = 0; ni < 4; ++ni) {
        const int col = bn + wn + ni * 16 + lrow;
        const float bv = bias[col];
        #pragma unroll
        for (int mi = 0; mi < 8; ++mi) {
            const int row = bm + wm + mi * 16 + quad * 4;
            if constexpr (EPI == 2) {
                // write V^T directly: (N,T,E)[row=(n,t), col=(h,d)] -> Vt(N,H,D,T)
                const int n = row >> 11, tt = row & 2047;
                const int hh = col >> 7, dd = col & 127;
                unsigned short* dst = (unsigned short*)Cv +
                    (((size_t)(n * 16 + hh) * 128 + dd) * 2048 + tt);
                ushort4 w;
                w.x = f2bf((acc[mi][ni][0] + bv) * scale);
                w.y = f2bf((acc[mi][ni][1] + bv) * scale);
                w.z = f2bf((acc[mi][ni][2] + bv) * scale);
                w.w = f2bf((acc[mi][ni][3] + bv) * scale);
                *(ushort4*)dst = w;
            } else {
                #pragma unroll
                for (int i = 0; i < 4; ++i) {
                    const float v = (acc[mi][ni][i] + bv) * scale;
                    if constexpr (EPI == 1)
                        ((unsigned short*)Cv)[(size_t)(row + i) * Nd + col] = f2bf(v);
                    else
                        ((float*)Cv)[(size_t)(row + i) * Nd + col] = v;
                }
            }
        }
    }
}

// ---------------------------------------------------------------------------
// Mask tile summary: per 128x128 tile of mask[T,S]: 0=all-zero, 1=mixed, 2=all-ones
// ---------------------------------------------------------------------------
__global__ __launch_bounds__(256)
void mask_tiles(const int* __restrict__ mask, unsigned char* __restrict__ flags)
{
    __shared__ int s_and, s_or;
    const int tid = threadIdx.x;
    if (tid == 0) { s_and = 1; s_or = 0; }
    __syncthreads();
    const int tt = blockIdx.x >> 4;
    const int ss = blockIdx.x & 15;
    int la = 1, lo = 0;
    #pragma unroll
    for (int it = 0; it < 16; ++it) {
        const int c = it * 256 + tid;
        const int row = c >> 5, c4 = c & 31;
        const int4 v = *(const int4*)(mask + (size_t)(tt * 128 + row) * SLEN + ss * 128 + c4 * 4);
        const int nz = (v.x != 0) + (v.y != 0) + (v.z != 0) + (v.w != 0);
        la &= (nz == 4); lo |= (nz != 0);
    }
    if (!la) atomicAnd(&s_and, 0);
    if (lo)  atomicOr(&s_or, 1);
    __syncthreads();
    if (tid == 0) flags[blockIdx.x] = (unsigned char)(s_and ? 2 : (s_or ? 1 : 0));
}

// ---------------------------------------------------------------------------
// Flash attention (unchanged from measured 229 us version)
// ---------------------------------------------------------------------------
#define LDP2 40    // P chunk row stride (80 B)

__global__ __launch_bounds__(256, 2)
void flash_attn(const unsigned short* __restrict__ Q,
                const unsigned short* __restrict__ Kb,
                const unsigned short* __restrict__ Vt,
                const int* __restrict__ mask,
                const unsigned char* __restrict__ tflags,
                unsigned short* __restrict__ O)
{
    __shared__ __align__(16) unsigned short Ks[128 * 128];
    __shared__ __align__(16) unsigned short Vs[128 * 128];
    __shared__ __align__(16) unsigned short Ps[4][32 * LDP2];

    const int tid  = threadIdx.x;
    const int lin  = blockIdx.x + 16 * (blockIdx.y + 16 * blockIdx.z);
    const int nlin = (lin & 7) * 128 + (lin >> 3);
    const int s0   = (nlin & 15) * 128;
    const int h    = (nlin >> 4) & 15;
    const int n    = nlin >> 8;
    const int wave = tid >> 6, lane = tid & 63;
    const int lrow = lane & 15, quad = lane >> 4;
    const int qbase = s0 + wave * 32;

    const int sr4 = lane >> 4;
    const int su  = lane & 15;

    const unsigned short* Kbase = Kb + (size_t)n * TLEN * NHEADS * DHEAD + (size_t)h * DHEAD;
    const unsigned short* Vbase = Vt + ((size_t)(n * NHEADS + h) * DHEAD) * TLEN;

    bf16x8 aq[2][4];
    #pragma unroll
    for (int si = 0; si < 2; ++si)
        #pragma unroll
        for (int kk = 0; kk < 4; ++kk)
            aq[si][kk] = *(const bf16x8*)(Q + ((size_t)(n * SLEN + qbase + si * 16 + lrow) * NHEADS + h) * DHEAD
                                            + kk * 32 + quad * 8);

    float m_r[2] = { -INFINITY, -INFINITY };
    float l_r[2] = { 0.f, 0.f };
    floatx4 occ[2][8] = {};

    for (int t0 = 0; t0 < TLEN; t0 += 128) {
        const int flag = tflags[(t0 >> 7) * (SLEN >> 7) + (s0 >> 7)];
        if (flag == 0) continue;

        #pragma unroll
        for (int i = 0; i < 8; ++i) {
            const int rb = wave * 32 + i * 4;
            const int r  = rb + sr4;
            const int uo = ((su ^ (r & 7)) * 8);
            gload16(Kbase + (size_t)(t0 + r) * (NHEADS * DHEAD) + uo, &Ks[rb * 128]);
            gload16(Vbase + (size_t)r * TLEN + t0 + uo,              &Vs[rb * 128]);
        }
        __syncthreads();

        floatx4 sacc[8][2] = {};
        __builtin_amdgcn_s_setprio(1);
        #pragma unroll
        for (int kk = 0; kk < 4; ++kk)
            #pragma unroll
            for (int ti = 0; ti < 8; ++ti) {
                const bf16x8 ak = *(const bf16x8*)&Ks[(ti * 16 + lrow) * 128
                                                      + ((kk * 4 + quad) ^ (lrow & 7)) * 8];
                sacc[ti][0] = __builtin_amdgcn_mfma_f32_16x16x32_bf16(ak, aq[0][kk], sacc[ti][0], 0, 0, 0);
                sacc[ti][1] = __builtin_amdgcn_mfma_f32_16x16x32_bf16(ak, aq[1][kk], sacc[ti][1], 0, 0, 0);
            }
        __builtin_amdgcn_s_setprio(0);

        if (flag == 1) {
            #pragma unroll
            for (int ti = 0; ti < 8; ++ti)
                #pragma unroll
                for (int si = 0; si < 2; ++si)
                    #pragma unroll
                    for (int i = 0; i < 4; ++i) {
                        const int t = t0 + ti * 16 + quad * 4 + i;
                        const int s = s0 + wave * 32 + si * 16 + lrow;
                        if (mask[(size_t)t * SLEN + s] == 0) sacc[ti][si][i] = -INFINITY;
                    }
        }

        float mt[2];
        #pragma unroll
        for (int si = 0; si < 2; ++si) {
            float v = sacc[0][si][0];
            #pragma unroll
            for (int ti = 0; ti < 8; ++ti)
                #pragma unroll
                for (int i = 0; i < 4; ++i) v = fmaxf(v, sacc[ti][si][i]);
            v = fmaxf(v, __shfl_xor(v, 16));
            v = fmaxf(v, __shfl_xor(v, 32));
            mt[si] = v;
        }

        float alpha[2] = { 1.f, 1.f };
        if (__any((mt[0] > m_r[0] + 8.f) || (mt[1] > m_r[1] + 8.f))) {
            float ao[2][4];
            #pragma unroll
            for (int si = 0; si < 2; ++si) {
                const float mnew = fmaxf(m_r[si], mt[si]);
                alpha[si] = (mnew == -INFINITY) ? 0.f : exp2f(m_r[si] - mnew);
                m_r[si] = mnew;
                #pragma unroll
                for (int i = 0; i < 4; ++i)
                    ao[si][i] = __shfl(alpha[si], quad * 4 + i);
            }
            #pragma unroll
            for (int si = 0; si < 2; ++si)
                #pragma unroll
                for (int nd = 0; nd < 8; ++nd)
                    #pragma unroll
                    for (int i = 0; i < 4; ++i)
                        occ[si][nd][i] *= ao[si][i];
        }
        const float msub[2] = { (m_r[0] == -INFINITY) ? 0.f : m_r[0],
                                (m_r[1] == -INFINITY) ? 0.f : m_r[1] };

        float psum[2] = { 0.f, 0.f };
        #pragma unroll
        for (int kk = 0; kk < 4; ++kk) {
            #pragma unroll
            for (int si = 0; si < 2; ++si)
                #pragma unroll
                for (int half = 0; half < 2; ++half) {
                    const int ti = kk * 2 + half;
                    float p[4];
                    #pragma unroll
                    for (int i = 0; i < 4; ++i)
                        p[i] = exp2f(sacc[ti][si][i] - msub[si]);
                    psum[si] += (p[0] + p[1]) + (p[2] + p[3]);
                    bf16x4 pb;
                    pb[0] = (__bf16)p[0]; pb[1] = (__bf16)p[1];
                    pb[2] = (__bf16)p[2]; pb[3] = (__bf16)p[3];
                    *(bf16x4*)&Ps[wave][(si * 16 + lrow) * LDP2 + half * 16 + quad * 4] = pb;
                }
            bf16x8 ap[2];
            #pragma unroll
            for (int si = 0; si < 2; ++si)
                ap[si] = *(const bf16x8*)&Ps[wave][(si * 16 + lrow) * LDP2 + quad * 8];
            __builtin_amdgcn_s_setprio(1);
            #pragma unroll
            for (int nd = 0; nd < 8; ++nd) {
                const bf16x8 bv = *(const bf16x8*)&Vs[(nd * 16 + lrow) * 128
                                                      + ((kk * 4 + quad) ^ (lrow & 7)) * 8];
                occ[0][nd] = __builtin_amdgcn_mfma_f32_16x16x32_bf16(ap[0], bv, occ[0][nd], 0, 0, 0);
                occ[1][nd] = __builtin_amdgcn_mfma_f32_16x16x32_bf16(ap[1], bv, occ[1][nd], 0, 0, 0);
            }
            __builtin_amdgcn_s_setprio(0);
        }

        #pragma unroll
        for (int si = 0; si < 2; ++si) {
            psum[si] += __shfl_xor(psum[si], 16);
            psum[si] += __shfl_xor(psum[si], 32);
            l_r[si] = l_r[si] * alpha[si] + psum[si];
        }
        __syncthreads();
    }

    float rl[2];
    #pragma unroll
    for (int si = 0; si < 2; ++si)
        rl[si] = (l_r[si] > 0.f) ? 1.0f / l_r[si] : 0.f;
    float rlo[2][4];
    #pragma unroll
    for (int si = 0; si < 2; ++si)
        #pragma unroll
        for (int i = 0; i < 4; ++i)
            rlo[si][i] = __shfl(rl[si], quad * 4 + i);

    #pragma unroll
    for (int si = 0; si < 2; ++si)
        #pragma unroll
        for (int nd = 0; nd < 8; ++nd)
            #pragma unroll
            for (int i = 0; i < 4; ++i) {
                const int srow = s0 + wave * 32 + si * 16 + quad * 4 + i;
                O[((size_t)(n * SLEN + srow) * NHEADS + h) * DHEAD + nd * 16 + lrow] =
                    f2bf(occ[si][nd][i] * rlo[si][i]);
            }
}

// ---------------------------------------------------------------------------
extern "C" void kernel_launch(void* const* d_in, const int* in_sizes, int n_in,
                              void* d_out, int out_size, void* d_ws, size_t ws_size,
                              hipStream_t stream)
{
    const float* query = (const float*)d_in[0];
    const float* key   = (const float*)d_in[1];
    const float* value = (const float*)d_in[2];
    const int*   mask  = (const int*)d_in[3];
    const float* Wq = (const float*)d_in[4];  const float* bq = (const float*)d_in[5];
    const float* Wk = (const float*)d_in[6];  const float* bk = (const float*)d_in[7];
    const float* Wv = (const float*)d_in[8];  const float* bv = (const float*)d_in[9];
    const float* Wp = (const float*)d_in[10]; const float* bp = (const float*)d_in[11];
    float* out = (float*)d_out;

    // ws layout (128 MB + 256 B): [Wb 32MB][A 32MB][B 32MB][C 32MB][flags]
    char* ws = (char*)d_ws;
    const size_t SLOT = 32ull * 1024 * 1024;
    unsigned short* Wb  = (unsigned short*)ws;              // 4 bf16 weights
    unsigned short* Abf = (unsigned short*)(ws + SLOT);     // q_bf -> later V^T
    unsigned short* Bbf = (unsigned short*)(ws + 2 * SLOT); // k_bf
    unsigned short* Cbf = (unsigned short*)(ws + 3 * SLOT); // v_bf -> later attn out
    unsigned char*  flags = (unsigned char*)(ws + 4 * SLOT);
    // Q/K projections parked in d_out (64 MB, dead before final GEMM writes it)
    unsigned short* Qb  = (unsigned short*)d_out;
    unsigned short* Kbb = (unsigned short*)((char*)d_out + SLOT);

    const size_t WSLOT = (size_t)E_DIM * E_DIM;
    const dim3 gg(MROWS / 256, E_DIM / 256);   // (32, 8), 512 threads
    const float sc = 0.08838834764831845f * 1.4426950408889634f; // 1/sqrt(128)*log2(e)

    mask_tiles<<<256, 256, 0, stream>>>(mask, flags);
    conv_qkv<<<dim3(8192, 3), 256, 0, stream>>>(query, key, value, Abf);
    conv_w<<<dim3(2048, 4), 256, 0, stream>>>(Wq, Wk, Wv, Wp, Wb);

    gemm256<1><<<gg, 512, 0, stream>>>(Abf, Wb,             bq, Qb,  MROWS, E_DIM, E_DIM, sc);
    gemm256<1><<<gg, 512, 0, stream>>>(Bbf, Wb + WSLOT,     bk, Kbb, MROWS, E_DIM, E_DIM, 1.f);
    gemm256<2><<<gg, 512, 0, stream>>>(Cbf, Wb + 2 * WSLOT, bv, Abf, MROWS, E_DIM, E_DIM, 1.f);
    flash_attn<<<dim3(SLEN / 128, NHEADS, NBATCH), 256, 0, stream>>>(Qb, Kbb, Abf, mask, flags, Cbf);
    gemm256<0><<<gg, 512, 0, stream>>>(Cbf, Wb + 3 * WSLOT, bp, out, MROWS, E_DIM, E_DIM, 1.f);
}

// Round 12
// 769.218 us; speedup vs baseline: 1.0388x; 1.0194x over previous
//
#include <hip/hip_runtime.h>

#define E_DIM   2048
#define NHEADS  16
#define NBATCH  4
#define SLEN    2048
#define TLEN    2048
#define DHEAD   128
#define MROWS   (NBATCH * SLEN)   // 8192

typedef __bf16  bf16x8  __attribute__((ext_vector_type(8)));
typedef __bf16  bf16x4  __attribute__((ext_vector_type(4)));
typedef float   floatx4 __attribute__((ext_vector_type(4)));
typedef unsigned short ushort8_v __attribute__((ext_vector_type(8)));

// fp32 -> bf16 RTNE via compiler cast
__device__ __forceinline__ unsigned short f2bf(float f) {
    return __builtin_bit_cast(unsigned short, (__bf16)f);
}

// async global->LDS, 16 B per lane: LDS dest = wave-uniform base + lane*16
__device__ __forceinline__ void gload16(const unsigned short* g, unsigned short* l) {
    __builtin_amdgcn_global_load_lds(
        (const __attribute__((address_space(1))) unsigned int*)(const void*)g,
        (__attribute__((address_space(3))) unsigned int*)(void*)l, 16, 0, 0);
}

// raw barrier with compile-time memory fences (no vmcnt(0) drain)
__device__ __forceinline__ void bar() {
    asm volatile("" ::: "memory");
    __builtin_amdgcn_s_barrier();
    asm volatile("" ::: "memory");
}

// ---------------------------------------------------------------------------
// fp32 -> bf16 conversion kernels
// ---------------------------------------------------------------------------
__global__ __launch_bounds__(256)
void conv_qkv(const float* __restrict__ q, const float* __restrict__ k,
              const float* __restrict__ v, unsigned short* __restrict__ dst)
{
    const float* src = (blockIdx.y == 0) ? q : ((blockIdx.y == 1) ? k : v);
    const size_t base = (size_t)blockIdx.y * ((size_t)MROWS * E_DIM);
    const size_t i = ((size_t)blockIdx.x * 256 + threadIdx.x) * 8;
    const float4 a = *(const float4*)(src + i);
    const float4 b = *(const float4*)(src + i + 4);
    ushort8_v o;
    o[0]=f2bf(a.x); o[1]=f2bf(a.y); o[2]=f2bf(a.z); o[3]=f2bf(a.w);
    o[4]=f2bf(b.x); o[5]=f2bf(b.y); o[6]=f2bf(b.z); o[7]=f2bf(b.w);
    *(ushort8_v*)(dst + base + i) = o;
}

__global__ __launch_bounds__(256)
void conv_w(const float* __restrict__ w0, const float* __restrict__ w1,
            const float* __restrict__ w2, const float* __restrict__ w3,
            unsigned short* __restrict__ dst)
{
    const float* src = (blockIdx.y == 0) ? w0 : ((blockIdx.y == 1) ? w1 :
                       ((blockIdx.y == 2) ? w2 : w3));
    const size_t base = (size_t)blockIdx.y * ((size_t)E_DIM * E_DIM);
    const size_t i = ((size_t)blockIdx.x * 256 + threadIdx.x) * 8;
    const float4 a = *(const float4*)(src + i);
    const float4 b = *(const float4*)(src + i + 4);
    ushort8_v o;
    o[0]=f2bf(a.x); o[1]=f2bf(a.y); o[2]=f2bf(a.z); o[3]=f2bf(a.w);
    o[4]=f2bf(b.x); o[5]=f2bf(b.y); o[6]=f2bf(b.z); o[7]=f2bf(b.w);
    *(ushort8_v*)(dst + base + i) = o;
}

// ---------------------------------------------------------------------------
// 256x256 GEMM, m201-faithful 8-phase/2-K-tile schedule.
// 8 waves (2Mx4N): wave output 128x64. LDS [slot:2][half:2][128][64] per
// matrix = 128 KB total. Half-tile staging (2 gload16 = 128 rows x 64 col),
// progressive-overwrite: B halves die after phase 1/5, A rows 0-63 after
// phase 2/6, A rows 64-127 after phase 4/8 (sealed by trailing barriers), so
// tile t+2 stages into tile t's regions during phases 2-8 + next-P1.
// Issue order/iter: P1:A(O)s1  P2,P3:B(E2)  P4:A(E2)s0  P5:A(E2)s1
// P6,P7:B(O2)  P8:A(O2)s0. vmcnt(6) ONLY at P4 & P8: each retires exactly
// the 8 issues of the next-consumed tile (youngest issued 3 phases earlier),
// keeping 6 in flight. Tail: last iter P4 = vmcnt(0).
// Swizzle: phys_unit = log_unit ^ (row&7), both-sides involution (rule #21).
// EPI: 0 = fp32 std, 1 = bf16 std, 2 = bf16 direct-V^T.
// ---------------------------------------------------------------------------
template<int EPI>
__global__ __launch_bounds__(512, 2)
void gemm256(const unsigned short* __restrict__ A, const unsigned short* __restrict__ B,
             const float* __restrict__ bias, void* __restrict__ Cv,
             int M, int Nd, int K, float scale)
{
    __shared__ unsigned short As[32768];   // [slot][half][row:128][col:64]
    __shared__ unsigned short Bs[32768];

    const int tid  = threadIdx.x;
    const int bm   = blockIdx.x * 256;
    const int bn   = blockIdx.y * 256;
    const int wave = tid >> 6, lane = tid & 63;
    const int wm   = (wave >> 2) * 128;    // 2 wave-rows
    const int wn   = (wave & 3) * 64;      // 4 wave-cols
    const int lrow = lane & 15, quad = lane >> 4;
    const int ha   = wm >> 7;              // wave's A half (0/1)
    const int hb   = wn >> 7;              // wave's B half
    const int wnr  = wn & 64;              // row base within B half
    const int u0   = (quad ^ (lrow & 7)) * 8;         // kk=0 phys unit
    const int u1   = ((4 + quad) ^ (lrow & 7)) * 8;   // kk=1

    // staging: thread -> row tid>>3 within 64-row issue, unit tid&7;
    // global col pre-swizzled by the same involution
    const int srow = tid >> 3;
    const int scol = ((tid & 7) ^ (srow & 7)) * 8;
    const unsigned short* ag = A + (size_t)(bm + srow) * K + scol;
    const unsigned short* bg = B + (size_t)(bn + srow) * K + scol;
    const int ldsw = wave * 512;           // wave's 8-row slice per issue

#define STG(Ls, Gp, T, H, S) \
    gload16((Gp) + (size_t)((H) * 128 + (S) * 64) * K + (size_t)(T) * 64, \
            (Ls) + (((T) & 1) << 14) + ((H) << 13) + ((S) << 12) + ldsw)
#define LDA(mi_, u_, s_) (*(const bf16x8*)&As[((s_) << 14) + (ha << 13) + (((mi_) * 16 + lrow) << 6) + (u_)])
#define LDB(ni_, u_, s_) (*(const bf16x8*)&Bs[((s_) << 14) + (hb << 13) + ((wnr + (ni_) * 16 + lrow) << 6) + (u_)])
#define MM16(m0) \
    __builtin_amdgcn_s_setprio(1); \
    _Pragma("unroll") \
    for (int ni = 0; ni < 4; ++ni) { \
        acc[(m0)][ni]     = __builtin_amdgcn_mfma_f32_16x16x32_bf16(af[0][0], rb[ni][0], acc[(m0)][ni], 0, 0, 0); \
        acc[(m0)][ni]     = __builtin_amdgcn_mfma_f32_16x16x32_bf16(af[0][1], rb[ni][1], acc[(m0)][ni], 0, 0, 0); \
        acc[(m0) + 1][ni] = __builtin_amdgcn_mfma_f32_16x16x32_bf16(af[1][0], rb[ni][0], acc[(m0) + 1][ni], 0, 0, 0); \
        acc[(m0) + 1][ni] = __builtin_amdgcn_mfma_f32_16x16x32_bf16(af[1][1], rb[ni][1], acc[(m0) + 1][ni], 0, 0, 0); \
    } \
    __builtin_amdgcn_s_setprio(0);

    floatx4 acc[8][4] = {};
    const int nit = K / 128;               // 2 K-tiles per iteration

    // prologue = virtual iter -1 phases P2..P8: tile0 complete + tile1 {B,A.s0}
    STG(Bs, bg, 0, 0, 0); STG(Bs, bg, 0, 0, 1);
    STG(Bs, bg, 0, 1, 0); STG(Bs, bg, 0, 1, 1);
    STG(As, ag, 0, 0, 0); STG(As, ag, 0, 1, 0);
    STG(As, ag, 0, 0, 1); STG(As, ag, 0, 1, 1);
    STG(Bs, bg, 1, 0, 0); STG(Bs, bg, 1, 0, 1);
    STG(Bs, bg, 1, 1, 0); STG(Bs, bg, 1, 1, 1);
    STG(As, ag, 1, 0, 0); STG(As, ag, 1, 1, 0);
    asm volatile("s_waitcnt vmcnt(6)" ::: "memory");   // tile 0 landed; 6 in flight
    bar();

    bf16x8 rb[4][2];
    for (int it = 0; it < nit; ++it) {
        const int O  = 2 * it + 1;
        const int E2 = 2 * it + 2;
        const int O2 = 2 * it + 3;
        const bool pf = (it + 1 < nit);
        bf16x8 af[2][2];

        // ---- P1: q0 slot0 (tile E) ----
        #pragma unroll
        for (int ni = 0; ni < 4; ++ni) { rb[ni][0] = LDB(ni, u0, 0); rb[ni][1] = LDB(ni, u1, 0); }
        af[0][0] = LDA(0, u0, 0); af[0][1] = LDA(0, u1, 0);
        af[1][0] = LDA(1, u0, 0); af[1][1] = LDA(1, u1, 0);
        STG(As, ag, O, 0, 1); STG(As, ag, O, 1, 1);    // finish tile O (A rows 64-127)
        bar();
        MM16(0);
        bar();

        // ---- P2: q1 slot0 ----
        af[0][0] = LDA(2, u0, 0); af[0][1] = LDA(2, u1, 0);
        af[1][0] = LDA(3, u0, 0); af[1][1] = LDA(3, u1, 0);
        if (pf) { STG(Bs, bg, E2, 0, 0); STG(Bs, bg, E2, 0, 1); }  // over dead B(E).h0
        bar();
        MM16(2);
        bar();

        // ---- P3: q2 slot0 ----
        af[0][0] = LDA(4, u0, 0); af[0][1] = LDA(4, u1, 0);
        af[1][0] = LDA(5, u0, 0); af[1][1] = LDA(5, u1, 0);
        if (pf) { STG(Bs, bg, E2, 1, 0); STG(Bs, bg, E2, 1, 1); }
        bar();
        MM16(4);
        bar();

        // ---- P4: q3 slot0 ----
        af[0][0] = LDA(6, u0, 0); af[0][1] = LDA(6, u1, 0);
        af[1][0] = LDA(7, u0, 0); af[1][1] = LDA(7, u1, 0);
        if (pf) { STG(As, ag, E2, 0, 0); STG(As, ag, E2, 1, 0); }  // over dead A(E) rows 0-63
        if (pf) asm volatile("s_waitcnt vmcnt(6)" ::: "memory");   // retires tile O's 8 issues
        else    asm volatile("s_waitcnt vmcnt(0)" ::: "memory");   // tail drain
        bar();                                                     // publish tile O
        MM16(6);
        bar();

        // ---- P5: q0 slot1 (tile O) ----
        #pragma unroll
        for (int ni = 0; ni < 4; ++ni) { rb[ni][0] = LDB(ni, u0, 1); rb[ni][1] = LDB(ni, u1, 1); }
        af[0][0] = LDA(0, u0, 1); af[0][1] = LDA(0, u1, 1);
        af[1][0] = LDA(1, u0, 1); af[1][1] = LDA(1, u1, 1);
        if (pf) { STG(As, ag, E2, 0, 1); STG(As, ag, E2, 1, 1); }  // over dead A(E) rows 64-127
        bar();
        MM16(0);
        bar();

        // ---- P6: q1 slot1 ----
        af[0][0] = LDA(2, u0, 1); af[0][1] = LDA(2, u1, 1);
        af[1][0] = LDA(3, u0, 1); af[1][1] = LDA(3, u1, 1);
        if (pf) { STG(Bs, bg, O2, 0, 0); STG(Bs, bg, O2, 0, 1); }  // over dead B(O).h0
        bar();
        MM16(2);
        bar();

        // ---- P7: q2 slot1 ----
        af[0][0] = LDA(4, u0, 1); af[0][1] = LDA(4, u1, 1);
        af[1][0] = LDA(5, u0, 1); af[1][1] = LDA(5, u1, 1);
        if (pf) { STG(Bs, bg, O2, 1, 0); STG(Bs, bg, O2, 1, 1); }
        bar();
        MM16(4);
        bar();

        // ---- P8: q3 slot1 ----
        af[0][0] = LDA(6, u0, 1); af[0][1] = LDA(6, u1, 1);
        af[1][0] = LDA(7, u0, 1); af[1][1] = LDA(7, u1, 1);
        if (pf) { STG(As, ag, O2, 0, 0); STG(As, ag, O2, 1, 0); }  // over dead A(O) rows 0-63
        asm volatile("s_waitcnt vmcnt(6)" ::: "memory");           // retires tile E2 (no-op on tail)
        bar();                                                     // publish tile E2
        MM16(6);
        bar();
    }
#undef STG
#undef LDA
#undef LDB
#undef MM16

    // epilogue: C/D layout col=lane&15, row=quad*4+i
    #pragma unroll
    for (int ni = 0; ni < 4; ++ni) {
        const int col = bn + wn + ni * 16 + lrow;
        const float bv = bias[col];
        #pragma unroll
        for (int mi = 0; mi < 8; ++mi) {
            const int row = bm + wm + mi * 16 + quad * 4;
            if constexpr (EPI == 2) {
                // write V^T directly: (N,T,E)[row=(n,t), col=(h,d)] -> Vt(N,H,D,T)
                const int n = row >> 11, tt = row & 2047;
                const int hh = col >> 7, dd = col & 127;
                unsigned short* dst = (unsigned short*)Cv +
                    (((size_t)(n * 16 + hh) * 128 + dd) * 2048 + tt);
                ushort4 w;
                w.x = f2bf((acc[mi][ni][0] + bv) * scale);
                w.y = f2bf((acc[mi][ni][1] + bv) * scale);
                w.z = f2bf((acc[mi][ni][2] + bv) * scale);
                w.w = f2bf((acc[mi][ni][3] + bv) * scale);
                *(ushort4*)dst = w;
            } else {
                #pragma unroll
                for (int i = 0; i < 4; ++i) {
                    const float v = (acc[mi][ni][i] + bv) * scale;
                    if constexpr (EPI == 1)
                        ((unsigned short*)Cv)[(size_t)(row + i) * Nd + col] = f2bf(v);
                    else
                        ((float*)Cv)[(size_t)(row + i) * Nd + col] = v;
                }
            }
        }
    }
}

// ---------------------------------------------------------------------------
// Mask tile summary: per 128x128 tile of mask[T,S]: 0=all-zero, 1=mixed, 2=all-ones
// ---------------------------------------------------------------------------
__global__ __launch_bounds__(256)
void mask_tiles(const int* __restrict__ mask, unsigned char* __restrict__ flags)
{
    __shared__ int s_and, s_or;
    const int tid = threadIdx.x;
    if (tid == 0) { s_and = 1; s_or = 0; }
    __syncthreads();
    const int tt = blockIdx.x >> 4;
    const int ss = blockIdx.x & 15;
    int la = 1, lo = 0;
    #pragma unroll
    for (int it = 0; it < 16; ++it) {
        const int c = it * 256 + tid;
        const int row = c >> 5, c4 = c & 31;
        const int4 v = *(const int4*)(mask + (size_t)(tt * 128 + row) * SLEN + ss * 128 + c4 * 4);
        const int nz = (v.x != 0) + (v.y != 0) + (v.z != 0) + (v.w != 0);
        la &= (nz == 4); lo |= (nz != 0);
    }
    if (!la) atomicAnd(&s_and, 0);
    if (lo)  atomicOr(&s_or, 1);
    __syncthreads();
    if (tid == 0) flags[blockIdx.x] = (unsigned char)(s_and ? 2 : (s_or ? 1 : 0));
}

// ---------------------------------------------------------------------------
// Flash attention (unchanged from measured 225 us version)
// ---------------------------------------------------------------------------
#define LDP2 40    // P chunk row stride (80 B)

__global__ __launch_bounds__(256, 2)
void flash_attn(const unsigned short* __restrict__ Q,
                const unsigned short* __restrict__ Kb,
                const unsigned short* __restrict__ Vt,
                const int* __restrict__ mask,
                const unsigned char* __restrict__ tflags,
                unsigned short* __restrict__ O)
{
    __shared__ __align__(16) unsigned short Ks[128 * 128];
    __shared__ __align__(16) unsigned short Vs[128 * 128];
    __shared__ __align__(16) unsigned short Ps[4][32 * LDP2];

    const int tid  = threadIdx.x;
    const int lin  = blockIdx.x + 16 * (blockIdx.y + 16 * blockIdx.z);
    const int nlin = (lin & 7) * 128 + (lin >> 3);
    const int s0   = (nlin & 15) * 128;
    const int h    = (nlin >> 4) & 15;
    const int n    = nlin >> 8;
    const int wave = tid >> 6, lane = tid & 63;
    const int lrow = lane & 15, quad = lane >> 4;
    const int qbase = s0 + wave * 32;

    const int sr4 = lane >> 4;
    const int su  = lane & 15;

    const unsigned short* Kbase = Kb + (size_t)n * TLEN * NHEADS * DHEAD + (size_t)h * DHEAD;
    const unsigned short* Vbase = Vt + ((size_t)(n * NHEADS + h) * DHEAD) * TLEN;

    bf16x8 aq[2][4];
    #pragma unroll
    for (int si = 0; si < 2; ++si)
        #pragma unroll
        for (int kk = 0; kk < 4; ++kk)
            aq[si][kk] = *(const bf16x8*)(Q + ((size_t)(n * SLEN + qbase + si * 16 + lrow) * NHEADS + h) * DHEAD
                                            + kk * 32 + quad * 8);

    float m_r[2] = { -INFINITY, -INFINITY };
    float l_r[2] = { 0.f, 0.f };
    floatx4 occ[2][8] = {};

    for (int t0 = 0; t0 < TLEN; t0 += 128) {
        const int flag = tflags[(t0 >> 7) * (SLEN >> 7) + (s0 >> 7)];
        if (flag == 0) continue;

        #pragma unroll
        for (int i = 0; i < 8; ++i) {
            const int rb = wave * 32 + i * 4;
            const int r  = rb + sr4;
            const int uo = ((su ^ (r & 7)) * 8);
            gload16(Kbase + (size_t)(t0 + r) * (NHEADS * DHEAD) + uo, &Ks[rb * 128]);
            gload16(Vbase + (size_t)r * TLEN + t0 + uo,              &Vs[rb * 128]);
        }
        __syncthreads();

        floatx4 sacc[8][2] = {};
        __builtin_amdgcn_s_setprio(1);
        #pragma unroll
        for (int kk = 0; kk < 4; ++kk)
            #pragma unroll
            for (int ti = 0; ti < 8; ++ti) {
                const bf16x8 ak = *(const bf16x8*)&Ks[(ti * 16 + lrow) * 128
                                                      + ((kk * 4 + quad) ^ (lrow & 7)) * 8];
                sacc[ti][0] = __builtin_amdgcn_mfma_f32_16x16x32_bf16(ak, aq[0][kk], sacc[ti][0], 0, 0, 0);
                sacc[ti][1] = __builtin_amdgcn_mfma_f32_16x16x32_bf16(ak, aq[1][kk], sacc[ti][1], 0, 0, 0);
            }
        __builtin_amdgcn_s_setprio(0);

        if (flag == 1) {
            #pragma unroll
            for (int ti = 0; ti < 8; ++ti)
                #pragma unroll
                for (int si = 0; si < 2; ++si)
                    #pragma unroll
                    for (int i = 0; i < 4; ++i) {
                        const int t = t0 + ti * 16 + quad * 4 + i;
                        const int s = s0 + wave * 32 + si * 16 + lrow;
                        if (mask[(size_t)t * SLEN + s] == 0) sacc[ti][si][i] = -INFINITY;
                    }
        }

        float mt[2];
        #pragma unroll
        for (int si = 0; si < 2; ++si) {
            float v = sacc[0][si][0];
            #pragma unroll
            for (int ti = 0; ti < 8; ++ti)
                #pragma unroll
                for (int i = 0; i < 4; ++i) v = fmaxf(v, sacc[ti][si][i]);
            v = fmaxf(v, __shfl_xor(v, 16));
            v = fmaxf(v, __shfl_xor(v, 32));
            mt[si] = v;
        }

        float alpha[2] = { 1.f, 1.f };
        if (__any((mt[0] > m_r[0] + 8.f) || (mt[1] > m_r[1] + 8.f))) {
            float ao[2][4];
            #pragma unroll
            for (int si = 0; si < 2; ++si) {
                const float mnew = fmaxf(m_r[si], mt[si]);
                alpha[si] = (mnew == -INFINITY) ? 0.f : exp2f(m_r[si] - mnew);
                m_r[si] = mnew;
                #pragma unroll
                for (int i = 0; i < 4; ++i)
                    ao[si][i] = __shfl(alpha[si], quad * 4 + i);
            }
            #pragma unroll
            for (int si = 0; si < 2; ++si)
                #pragma unroll
                for (int nd = 0; nd < 8; ++nd)
                    #pragma unroll
                    for (int i = 0; i < 4; ++i)
                        occ[si][nd][i] *= ao[si][i];
        }
        const float msub[2] = { (m_r[0] == -INFINITY) ? 0.f : m_r[0],
                                (m_r[1] == -INFINITY) ? 0.f : m_r[1] };

        float psum[2] = { 0.f, 0.f };
        #pragma unroll
        for (int kk = 0; kk < 4; ++kk) {
            #pragma unroll
            for (int si = 0; si < 2; ++si)
                #pragma unroll
                for (int half = 0; half < 2; ++half) {
                    const int ti = kk * 2 + half;
                    float p[4];
                    #pragma unroll
                    for (int i = 0; i < 4; ++i)
                        p[i] = exp2f(sacc[ti][si][i] - msub[si]);
                    psum[si] += (p[0] + p[1]) + (p[2] + p[3]);
                    bf16x4 pb;
                    pb[0] = (__bf16)p[0]; pb[1] = (__bf16)p[1];
                    pb[2] = (__bf16)p[2]; pb[3] = (__bf16)p[3];
                    *(bf16x4*)&Ps[wave][(si * 16 + lrow) * LDP2 + half * 16 + quad * 4] = pb;
                }
            bf16x8 ap[2];
            #pragma unroll
            for (int si = 0; si < 2; ++si)
                ap[si] = *(const bf16x8*)&Ps[wave][(si * 16 + lrow) * LDP2 + quad * 8];
            __builtin_amdgcn_s_setprio(1);
            #pragma unroll
            for (int nd = 0; nd < 8; ++nd) {
                const bf16x8 bv = *(const bf16x8*)&Vs[(nd * 16 + lrow) * 128
                                                      + ((kk * 4 + quad) ^ (lrow & 7)) * 8];
                occ[0][nd] = __builtin_amdgcn_mfma_f32_16x16x32_bf16(ap[0], bv, occ[0][nd], 0, 0, 0);
                occ[1][nd] = __builtin_amdgcn_mfma_f32_16x16x32_bf16(ap[1], bv, occ[1][nd], 0, 0, 0);
            }
            __builtin_amdgcn_s_setprio(0);
        }

        #pragma unroll
        for (int si = 0; si < 2; ++si) {
            psum[si] += __shfl_xor(psum[si], 16);
            psum[si] += __shfl_xor(psum[si], 32);
            l_r[si] = l_r[si] * alpha[si] + psum[si];
        }
        __syncthreads();
    }

    float rl[2];
    #pragma unroll
    for (int si = 0; si < 2; ++si)
        rl[si] = (l_r[si] > 0.f) ? 1.0f / l_r[si] : 0.f;
    float rlo[2][4];
    #pragma unroll
    for (int si = 0; si < 2; ++si)
        #pragma unroll
        for (int i = 0; i < 4; ++i)
            rlo[si][i] = __shfl(rl[si], quad * 4 + i);

    #pragma unroll
    for (int si = 0; si < 2; ++si)
        #pragma unroll
        for (int nd = 0; nd < 8; ++nd)
            #pragma unroll
            for (int i = 0; i < 4; ++i) {
                const int srow = s0 + wave * 32 + si * 16 + quad * 4 + i;
                O[((size_t)(n * SLEN + srow) * NHEADS + h) * DHEAD + nd * 16 + lrow] =
                    f2bf(occ[si][nd][i] * rlo[si][i]);
            }
}

// ---------------------------------------------------------------------------
extern "C" void kernel_launch(void* const* d_in, const int* in_sizes, int n_in,
                              void* d_out, int out_size, void* d_ws, size_t ws_size,
                              hipStream_t stream)
{
    const float* query = (const float*)d_in[0];
    const float* key   = (const float*)d_in[1];
    const float* value = (const float*)d_in[2];
    const int*   mask  = (const int*)d_in[3];
    const float* Wq = (const float*)d_in[4];  const float* bq = (const float*)d_in[5];
    const float* Wk = (const float*)d_in[6];  const float* bk = (const float*)d_in[7];
    const float* Wv = (const float*)d_in[8];  const float* bv = (const float*)d_in[9];
    const float* Wp = (const float*)d_in[10]; const float* bp = (const float*)d_in[11];
    float* out = (float*)d_out;

    // ws layout (128 MB + 256 B): [Wb 32MB][A 32MB][B 32MB][C 32MB][flags]
    char* ws = (char*)d_ws;
    const size_t SLOT = 32ull * 1024 * 1024;
    unsigned short* Wb  = (unsigned short*)ws;              // 4 bf16 weights
    unsigned short* Abf = (unsigned short*)(ws + SLOT);     // q_bf -> later V^T
    unsigned short* Bbf = (unsigned short*)(ws + 2 * SLOT); // k_bf
    unsigned short* Cbf = (unsigned short*)(ws + 3 * SLOT); // v_bf -> later attn out
    unsigned char*  flags = (unsigned char*)(ws + 4 * SLOT);
    // Q/K projections parked in d_out (64 MB, dead before final GEMM writes it)
    unsigned short* Qb  = (unsigned short*)d_out;
    unsigned short* Kbb = (unsigned short*)((char*)d_out + SLOT);

    const size_t WSLOT = (size_t)E_DIM * E_DIM;
    const dim3 gg(MROWS / 256, E_DIM / 256);   // (32, 8), 512 threads
    const float sc = 0.08838834764831845f * 1.4426950408889634f; // 1/sqrt(128)*log2(e)

    mask_tiles<<<256, 256, 0, stream>>>(mask, flags);
    conv_qkv<<<dim3(8192, 3), 256, 0, stream>>>(query, key, value, Abf);
    conv_w<<<dim3(2048, 4), 256, 0, stream>>>(Wq, Wk, Wv, Wp, Wb);

    gemm256<1><<<gg, 512, 0, stream>>>(Abf, Wb,             bq, Qb,  MROWS, E_DIM, E_DIM, sc);
    gemm256<1><<<gg, 512, 0, stream>>>(Bbf, Wb + WSLOT,     bk, Kbb, MROWS, E_DIM, E_DIM, 1.f);
    gemm256<2><<<gg, 512, 0, stream>>>(Cbf, Wb + 2 * WSLOT, bv, Abf, MROWS, E_DIM, E_DIM, 1.f);
    flash_attn<<<dim3(SLEN / 128, NHEADS, NBATCH), 256, 0, stream>>>(Qb, Kbb, Abf, mask, flags, Cbf);
    gemm256<0><<<gg, 512, 0, stream>>>(Cbf, Wb + 3 * WSLOT, bp, out, MROWS, E_DIM, E_DIM, 1.f);
}